// Round 4
// baseline (270.901 us; speedup 1.0000x reference)
//
#include <hip/hip_runtime.h>
#include <math.h>

// Problem constants
#define Bn   32
#define Cn   684
#define Hn   16
#define Wn   64
#define HWn  1024
#define HIDn 256
#define An   512
#define KKn  121           // 11*11
#define CREAL 805          // 684 + 121
#define CPAD 832           // 26 chunks of 32 (VTbf row stride)
#define NSTEP 26

// Output layout (flat fp32): context [32,684] | alpha [32,1024] | alpha_sum_new [32,1024]
#define OUT_ALPHA 21888
#define OUT_ASUM  (21888 + 32768)

typedef short short8 __attribute__((ext_vector_type(8)));     // 8 bf16 = 4 VGPRs
typedef float floatx4 __attribute__((ext_vector_type(4)));    // MFMA acc

__device__ __forceinline__ unsigned short f2bf(float f) {
    union { float f; unsigned int i; } v; v.f = f;
    unsigned int i = v.i;
    return (unsigned short)((i + 0x7fffu + ((i >> 16) & 1u)) >> 16);
}
__device__ __forceinline__ unsigned int pack2bf(float v0, float v1) {
    unsigned int u0 = __float_as_uint(v0), u1 = __float_as_uint(v1);
    u0 = (u0 + 0x7fffu + ((u0 >> 16) & 1u)) >> 16;
    u1 = (u1 + 0x7fffu + ((u1 >> 16) & 1u)) & 0xffff0000u;
    return u0 | u1;
}

// ---------------------------------------------------------------------------
// K_prep: fused  (blocks 0..511: build VTbf row a)  (blocks 512..543: query b)
//   VTbf [512 a][832 k] bf16, k-contiguous:
//     k 0..683   = Wec[a][k]
//     k 684..804 = Wfused[a][ij] = sum_c Waw[a,c]*Wac[c,ij]
//     k 805..831 = 0
//   query[b,a] = bh[a] + bec[a] + sum_h hidden[b,h]*Wh[a,h]
__global__ __launch_bounds__(256) void k_prep(
    const float* __restrict__ hidden,
    const float* __restrict__ Wh,
    const float* __restrict__ bh,
    const float* __restrict__ bec,
    const float* __restrict__ Wec,
    const float* __restrict__ Wac,
    const float* __restrict__ Waw,
    float* __restrict__ query,
    unsigned short* __restrict__ VTbf)
{
    __shared__ float sbuf[512];
    const int blk = blockIdx.x, t = threadIdx.x;
    if (blk < 512) {
        const int a = blk;
        sbuf[t]       = Waw[(size_t)a * 512 + t];
        sbuf[t + 256] = Waw[(size_t)a * 512 + t + 256];
        __syncthreads();
        for (int cp = t; cp < Cn; cp += 256)
            VTbf[(size_t)a * CPAD + cp] = f2bf(Wec[(size_t)a * Cn + cp]);
        if (t < KKn) {
            float s = 0.f;
            #pragma unroll 8
            for (int k = 0; k < 512; ++k)
                s = fmaf(sbuf[k], Wac[k * KKn + t], s);
            VTbf[(size_t)a * CPAD + Cn + t] = f2bf(s);
        }
        for (int cp = CREAL + t; cp < CPAD; cp += 256)
            VTbf[(size_t)a * CPAD + cp] = 0;
    } else {
        const int b = blk - 512;
        sbuf[t] = (t < HIDn) ? hidden[b * HIDn + t] : 0.f;
        __syncthreads();
        for (int a = t; a < An; a += 256) {
            const float4* wp = (const float4*)(Wh + (size_t)a * HIDn);
            float s = bh[a] + bec[a];
            #pragma unroll 8
            for (int i = 0; i < HIDn / 4; ++i) {
                float4 w = wp[i];
                s = fmaf(sbuf[4 * i],     w.x, s);
                s = fmaf(sbuf[4 * i + 1], w.y, s);
                s = fmaf(sbuf[4 * i + 2], w.z, s);
                s = fmaf(sbuf[4 * i + 3], w.w, s);
            }
            query[b * An + a] = s;
        }
    }
}

// ---------------------------------------------------------------------------
// K_energy v3: barrier-free MFMA K-loop, direct global fragment loads.
// Block = (b,h): M=64 pos, N=512 a (wave owns 128), K=832.
__global__ __launch_bounds__(256, 2) void k_energy(
    const float* __restrict__ X,
    const float* __restrict__ asum,
    const float* __restrict__ Wv,
    const float* __restrict__ query,
    const unsigned short* __restrict__ VTbf,
    float* __restrict__ energy)
{
    __shared__ float plane[11 * 74 + 2];   // padded alpha rows hh-5..hh+5
    __shared__ float qs[512];
    __shared__ float wvs[512];
    __shared__ float red[64 * 65];         // epilogue reduction

    const int t = threadIdx.x;
    const int hh = blockIdx.x, b = blockIdx.y;
    const int w = t >> 6, lane = t & 63;
    const int q = lane >> 4, r = lane & 15;

    for (int i = t; i < 11 * 74; i += 256) {
        int di = i / 74, cc = i - di * 74;
        int h2 = hh + di - 5, w2 = cc - 5;
        float v = 0.f;
        if (h2 >= 0 && h2 < Hn && w2 >= 0 && w2 < Wn)
            v = asum[b * HWn + h2 * Wn + w2];
        plane[i] = v;
    }
    qs[t]        = query[b * An + t];
    qs[t + 256]  = query[b * An + t + 256];
    wvs[t]       = Wv[t];
    wvs[t + 256] = Wv[t + 256];
    __syncthreads();   // one-time (plane/qs/wvs)

    floatx4 acc[4][8];
    #pragma unroll
    for (int mf = 0; mf < 4; ++mf)
        #pragma unroll
        for (int nf = 0; nf < 8; ++nf)
            acc[mf][nf] = (floatx4){0.f, 0.f, 0.f, 0.f};

    const float* Xb = X + (size_t)b * Cn * HWn + hh * Wn;       // + row*1024 + m
    const unsigned short* Bb = VTbf + (size_t)(w * 128) * CPAD; // wave's n-panel

    // ---- steps 0..20: pure-X fast path (rows c0..c0+31 all < 684)
    for (int ch = 0; ch < 21; ++ch) {
        const int c0 = ch * 32;
        short8 bfr[8];
        #pragma unroll
        for (int nf = 0; nf < 8; ++nf)
            bfr[nf] = *(const short8*)(Bb + (size_t)(nf * 16 + r) * CPAD + c0 + q * 8);
        short8 af[4];
        #pragma unroll
        for (int mf = 0; mf < 4; ++mf) {
            const int m = mf * 16 + r;
            const float* xp = Xb + (size_t)(c0 + q * 8) * HWn + m;
            unsigned int pk[4];
            #pragma unroll
            for (int jj = 0; jj < 4; ++jj)
                pk[jj] = pack2bf(xp[(size_t)(2 * jj) * HWn], xp[(size_t)(2 * jj + 1) * HWn]);
            union { unsigned int u[4]; short8 s; } cv;
            cv.u[0] = pk[0]; cv.u[1] = pk[1]; cv.u[2] = pk[2]; cv.u[3] = pk[3];
            af[mf] = cv.s;
        }
        #pragma unroll
        for (int mf = 0; mf < 4; ++mf)
            #pragma unroll
            for (int nf = 0; nf < 8; ++nf)
                acc[mf][nf] = __builtin_amdgcn_mfma_f32_16x16x32_bf16(
                    af[mf], bfr[nf], acc[mf][nf], 0, 0, 0);
    }
    // ---- steps 21..25: mixed X / im2col(plane) / zero rows
    for (int ch = 21; ch < NSTEP; ++ch) {
        const int c0 = ch * 32;
        short8 bfr[8];
        #pragma unroll
        for (int nf = 0; nf < 8; ++nf)
            bfr[nf] = *(const short8*)(Bb + (size_t)(nf * 16 + r) * CPAD + c0 + q * 8);
        short8 af[4];
        #pragma unroll
        for (int mf = 0; mf < 4; ++mf) {
            const int m = mf * 16 + r;
            float v[8];
            #pragma unroll
            for (int jj = 0; jj < 8; ++jj) {
                int row = c0 + q * 8 + jj;
                float x;
                if (row < Cn) {
                    x = Xb[(size_t)row * HWn + m];
                } else if (row < CREAL) {
                    int ij = row - Cn; int di = ij / 11, dj = ij - di * 11;
                    x = plane[di * 74 + m + dj];
                } else {
                    x = 0.f;
                }
                v[jj] = x;
            }
            union { unsigned int u[4]; short8 s; } cv;
            #pragma unroll
            for (int jj = 0; jj < 4; ++jj)
                cv.u[jj] = pack2bf(v[2 * jj], v[2 * jj + 1]);
            af[mf] = cv.s;
        }
        #pragma unroll
        for (int mf = 0; mf < 4; ++mf)
            #pragma unroll
            for (int nf = 0; nf < 8; ++nf)
                acc[mf][nf] = __builtin_amdgcn_mfma_f32_16x16x32_bf16(
                    af[mf], bfr[nf], acc[mf][nf], 0, 0, 0);
    }

    // ---- epilogue: e[m] = sum_n Wv[n]*tanh(acc + query[n])
    float ep[16];
    #pragma unroll
    for (int i = 0; i < 16; ++i) ep[i] = 0.f;
    #pragma unroll
    for (int nf = 0; nf < 8; ++nf) {
        int n = w * 128 + nf * 16 + r;
        float qv = qs[n], wv = wvs[n];
        #pragma unroll
        for (int mf = 0; mf < 4; ++mf)
            #pragma unroll
            for (int rg = 0; rg < 4; ++rg) {
                float x = acc[mf][nf][rg] + qv;
                float e2 = __expf(2.f * x);
                float th = 1.f - 2.f * __builtin_amdgcn_rcpf(e2 + 1.f);
                ep[mf * 4 + rg] += wv * th;
            }
    }
    __syncthreads();
    #pragma unroll
    for (int mf = 0; mf < 4; ++mf)
        #pragma unroll
        for (int rg = 0; rg < 4; ++rg)
            red[(mf * 16 + q * 4 + rg) * 65 + w * 16 + r] = ep[mf * 4 + rg];
    __syncthreads();
    if (t < 64) {
        float s = 0.f;
        #pragma unroll 16
        for (int i = 0; i < 64; ++i) s += red[t * 65 + i];
        energy[b * HWn + hh * Wn + t] = s;
    }
}

// ---------------------------------------------------------------------------
// K_softmax: per-batch row-max (softmax is shift-invariant => identical alpha),
// exp/sum, writes alpha + alpha_sum_new.
__global__ __launch_bounds__(1024) void k_softmax(
    const float* __restrict__ energy,
    const float* __restrict__ mask, const float* __restrict__ asum,
    float* __restrict__ alpha_f, float* __restrict__ out)
{
    __shared__ float sm[16];
    __shared__ float bc[2];
    const int b = blockIdx.x, t = threadIdx.x;
    float e = energy[b * HWn + t];
    float m = e;
    for (int off = 32; off >= 1; off >>= 1) m = fmaxf(m, __shfl_down(m, off, 64));
    if ((t & 63) == 0) sm[t >> 6] = m;
    __syncthreads();
    if (t == 0) {
        float mm = sm[0];
        for (int i = 1; i < 16; ++i) mm = fmaxf(mm, sm[i]);
        bc[0] = mm;
    }
    __syncthreads();
    float ex = expf(e - bc[0]) * mask[b * HWn + t];
    float s = ex;
    for (int off = 32; off >= 1; off >>= 1) s += __shfl_down(s, off, 64);
    __syncthreads();
    if ((t & 63) == 0) sm[t >> 6] = s;
    __syncthreads();
    if (t == 0) {
        float tot = 0.f;
        for (int i = 0; i < 16; ++i) tot += sm[i];
        bc[1] = tot + 1e-10f;
    }
    __syncthreads();
    float alpha = ex / bc[1];
    alpha_f[b * HWn + t] = alpha;
    out[OUT_ALPHA + b * HWn + t] = alpha;
    out[OUT_ASUM  + b * HWn + t] = alpha + asum[b * HWn + t];
}

// ---------------------------------------------------------------------------
// K_context: context[b,c] = sum_hw alpha[b,hw]*X[b,c,hw]; one wave per c
__global__ __launch_bounds__(256) void k_context(
    const float* __restrict__ X, const float* __restrict__ alpha_f,
    float* __restrict__ out)
{
    const int t = threadIdx.x, lane = t & 63, wid = t >> 6;
    const int b = blockIdx.y;
    const int c = blockIdx.x * 4 + wid;
    const float* xp = X + ((size_t)(b * Cn + c)) * HWn;
    const float* ap = alpha_f + b * HWn;
    float s = 0.f;
    #pragma unroll
    for (int i = 0; i < 4; ++i) {
        int off = i * 256 + lane * 4;
        float4 x = *(const float4*)(xp + off);
        float4 a = *(const float4*)(ap + off);
        s = fmaf(a.x, x.x, s);
        s = fmaf(a.y, x.y, s);
        s = fmaf(a.z, x.z, s);
        s = fmaf(a.w, x.w, s);
    }
    for (int off = 32; off >= 1; off >>= 1) s += __shfl_down(s, off, 64);
    if (lane == 0) out[b * Cn + c] = s;
}

// ---------------------------------------------------------------------------
extern "C" void kernel_launch(void* const* d_in, const int* in_sizes, int n_in,
                              void* d_out, int out_size, void* d_ws, size_t ws_size,
                              hipStream_t stream)
{
    const float* X      = (const float*)d_in[0];
    const float* hidden = (const float*)d_in[1];
    const float* asum   = (const float*)d_in[2];
    const float* mask   = (const float*)d_in[3];
    const float* Wh     = (const float*)d_in[4];
    const float* bh     = (const float*)d_in[5];
    const float* Wec    = (const float*)d_in[6];
    const float* bec    = (const float*)d_in[7];
    const float* Wac    = (const float*)d_in[8];
    const float* Waw    = (const float*)d_in[9];
    const float* Wv     = (const float*)d_in[10];
    (void)in_sizes; (void)n_in; (void)out_size; (void)ws_size;

    float* out = (float*)d_out;
    float* ws = (float*)d_ws;
    float* query   = ws;                                    // 16384 floats
    float* energy  = ws + 16384;                            // 32768
    float* alpha_f = ws + 16384 + 32768;                    // 32768
    unsigned short* VTbf = (unsigned short*)(ws + 81920);   // 512*832 ushorts

    k_prep    <<<dim3(544),     dim3(256),  0, stream>>>(hidden, Wh, bh, bec,
                                                         Wec, Wac, Waw, query, VTbf);
    k_energy  <<<dim3(16, 32),  dim3(256),  0, stream>>>(X, asum, Wv, query, VTbf, energy);
    k_softmax <<<dim3(32),      dim3(1024), 0, stream>>>(energy, mask, asum, alpha_f, out);
    k_context <<<dim3(171, 32), dim3(256),  0, stream>>>(X, alpha_f, out);
}

// Round 5
// 252.878 us; speedup vs baseline: 1.0713x; 1.0713x over previous
//
#include <hip/hip_runtime.h>
#include <math.h>

// Problem constants
#define Bn   32
#define Cn   684
#define Hn   16
#define Wn   64
#define HWn  1024
#define HIDn 256
#define An   512
#define KKn  121           // 11*11
#define CREAL 805          // 684 + 121
#define CPAD 832           // 26 chunks of 32 (VTbf row stride)
#define NSTEP 26
#define NBLK 256           // a-columns per energy block (N-split x2)

// Output layout (flat fp32): context [32,684] | alpha [32,1024] | alpha_sum_new [32,1024]
#define OUT_ALPHA 21888
#define OUT_ASUM  (21888 + 32768)

typedef short short8 __attribute__((ext_vector_type(8)));     // 8 bf16 = 4 VGPRs
typedef float floatx4 __attribute__((ext_vector_type(4)));    // MFMA acc

__device__ __forceinline__ unsigned short f2bf(float f) {
    union { float f; unsigned int i; } v; v.f = f;
    unsigned int i = v.i;
    return (unsigned short)((i + 0x7fffu + ((i >> 16) & 1u)) >> 16);
}
__device__ __forceinline__ unsigned int pack2bf(float v0, float v1) {
    unsigned int u0 = __float_as_uint(v0), u1 = __float_as_uint(v1);
    u0 = (u0 + 0x7fffu + ((u0 >> 16) & 1u)) >> 16;
    u1 = (u1 + 0x7fffu + ((u1 >> 16) & 1u)) & 0xffff0000u;
    return u0 | u1;
}
// async global->LDS, 16B per lane; lds base must be wave-uniform
__device__ __forceinline__ void async_lds16(void* lds, const void* g) {
    __builtin_amdgcn_global_load_lds(
        (const __attribute__((address_space(1))) unsigned int*)g,
        (__attribute__((address_space(3))) unsigned int*)lds, 16, 0, 0);
}

// ---------------------------------------------------------------------------
// K_prep: fused  (blocks 0..511: build VTbf row a)  (blocks 512..543: query b)
__global__ __launch_bounds__(256) void k_prep(
    const float* __restrict__ hidden,
    const float* __restrict__ Wh,
    const float* __restrict__ bh,
    const float* __restrict__ bec,
    const float* __restrict__ Wec,
    const float* __restrict__ Wac,
    const float* __restrict__ Waw,
    float* __restrict__ query,
    unsigned short* __restrict__ VTbf)
{
    __shared__ float sbuf[512];
    const int blk = blockIdx.x, t = threadIdx.x;
    if (blk < 512) {
        const int a = blk;
        sbuf[t]       = Waw[(size_t)a * 512 + t];
        sbuf[t + 256] = Waw[(size_t)a * 512 + t + 256];
        __syncthreads();
        for (int cp = t; cp < Cn; cp += 256)
            VTbf[(size_t)a * CPAD + cp] = f2bf(Wec[(size_t)a * Cn + cp]);
        if (t < KKn) {
            float s = 0.f;
            #pragma unroll 8
            for (int k = 0; k < 512; ++k)
                s = fmaf(sbuf[k], Wac[k * KKn + t], s);
            VTbf[(size_t)a * CPAD + Cn + t] = f2bf(s);
        }
        for (int cp = CREAL + t; cp < CPAD; cp += 256)
            VTbf[(size_t)a * CPAD + cp] = 0;
    } else {
        const int b = blk - 512;
        sbuf[t] = (t < HIDn) ? hidden[b * HIDn + t] : 0.f;
        __syncthreads();
        for (int a = t; a < An; a += 256) {
            const float4* wp = (const float4*)(Wh + (size_t)a * HIDn);
            float s = bh[a] + bec[a];
            #pragma unroll 8
            for (int i = 0; i < HIDn / 4; ++i) {
                float4 w = wp[i];
                s = fmaf(sbuf[4 * i],     w.x, s);
                s = fmaf(sbuf[4 * i + 1], w.y, s);
                s = fmaf(sbuf[4 * i + 2], w.z, s);
                s = fmaf(sbuf[4 * i + 3], w.w, s);
            }
            query[b * An + a] = s;
        }
    }
}

// ---------------------------------------------------------------------------
// K_energy v4: LDS-staged, double-buffered, ONE barrier per K-step.
// Grid (2, 16, 32): blockIdx.x = n-half (256 a's), y = hh, z = b.
// Block: 256 thr / 4 waves; wave owns 64 a (4 nf); M=64 pos; K=832.
__device__ __forceinline__ float fetchU(const float* __restrict__ X,
                                        const float* plane,
                                        int m, int row) {
    if (row < Cn)   return X[(size_t)row * HWn + m];
    if (row < CREAL) {
        int ij = row - Cn; int di = ij / 11, dj = ij - di * 11;
        return plane[di * 74 + m + dj];
    }
    return 0.f;
}

__global__ __launch_bounds__(256, 3) void k_energy(
    const float* __restrict__ X,
    const float* __restrict__ asum,
    const float* __restrict__ Wv,
    const float* __restrict__ query,
    const unsigned short* __restrict__ VTbf,
    float* __restrict__ energy)
{
    __shared__ unsigned short As[2 * 64 * 40];    // A dbuf [m][k], stride 40
    __shared__ unsigned short Bs[2 * 256 * 32];   // B dbuf [n][k]; reused as red
    __shared__ float plane[11 * 74 + 2];
    __shared__ float qs[NBLK];
    __shared__ float wvs[NBLK];

    const int t = threadIdx.x;
    const int nh = blockIdx.x, hh = blockIdx.y, b = blockIdx.z;
    const int w = t >> 6, lane = t & 63;
    const int q = lane >> 4, r = lane & 15;
    const int nbase = nh * NBLK;
    const int mA = t & 63;                 // A-staging: m index
    const int koA = t >> 6;                // A-staging: k-octet (0..3)

    const float* Xb = X + (size_t)b * Cn * HWn + hh * Wn;

    // ---- prologue: plane / qs / wvs / chunk 0
    for (int i = t; i < 11 * 74; i += 256) {
        int di = i / 74, cc = i - di * 74;
        int h2 = hh + di - 5, w2 = cc - 5;
        float v = 0.f;
        if (h2 >= 0 && h2 < Hn && w2 >= 0 && w2 < Wn)
            v = asum[b * HWn + h2 * Wn + w2];
        plane[i] = v;
    }
    qs[t]  = query[b * An + nbase + t];
    wvs[t] = Wv[nbase + t];
    // stage A chunk 0 (rows 0..31, pure X)
    {
        const float* xp = Xb + (size_t)(koA * 8) * HWn + mA;
        unsigned int pk[4];
        #pragma unroll
        for (int jj = 0; jj < 4; ++jj)
            pk[jj] = pack2bf(xp[(size_t)(2 * jj) * HWn], xp[(size_t)(2 * jj + 1) * HWn]);
        *(uint4*)&As[mA * 40 + koA * 8] = make_uint4(pk[0], pk[1], pk[2], pk[3]);
    }
    // stage B chunk 0 (XOR swizzle on global side)
    #pragma unroll
    for (int ii = 0; ii < 4; ++ii) {
        int n0 = w * 64 + ii * 16;
        int row = nbase + n0 + (lane >> 2);
        int gc = (lane & 3) ^ ((lane >> 2) & 3);
        async_lds16(&Bs[n0 * 32], VTbf + (size_t)row * CPAD + gc * 8);
    }
    __syncthreads();

    floatx4 acc[4][4];
    #pragma unroll
    for (int mf = 0; mf < 4; ++mf)
        #pragma unroll
        for (int nf = 0; nf < 4; ++nf)
            acc[mf][nf] = (floatx4){0.f, 0.f, 0.f, 0.f};

    for (int ch = 0; ch < NSTEP; ++ch) {
        const int cur = ch & 1;
        const unsigned short* Ab = As + cur * (64 * 40);
        const unsigned short* Bb = Bs + cur * (256 * 32);

        // (1) read fragments of current chunk
        short8 af[4], bfr[4];
        #pragma unroll
        for (int mf = 0; mf < 4; ++mf)
            af[mf] = *(const short8*)&Ab[(mf * 16 + r) * 40 + q * 8];
        #pragma unroll
        for (int nf = 0; nf < 4; ++nf)
            bfr[nf] = *(const short8*)&Bb[(w * 64 + nf * 16 + r) * 32 + (q ^ (r & 3)) * 8];

        // (2) stage next chunk into other buffer
        if (ch < NSTEP - 1) {
            const int c1 = (ch + 1) * 32;
            unsigned short* Bn_ = Bs + (cur ^ 1) * (256 * 32);
            #pragma unroll
            for (int ii = 0; ii < 4; ++ii) {
                int n0 = w * 64 + ii * 16;
                int row = nbase + n0 + (lane >> 2);
                int gc = (lane & 3) ^ ((lane >> 2) & 3);
                async_lds16(&Bn_[n0 * 32], VTbf + (size_t)row * CPAD + c1 + gc * 8);
            }
            unsigned int pk[4];
            if (c1 + 31 < Cn) {          // pure-X fast path (chunks 1..20)
                const float* xp = Xb + (size_t)(c1 + koA * 8) * HWn + mA;
                #pragma unroll
                for (int jj = 0; jj < 4; ++jj)
                    pk[jj] = pack2bf(xp[(size_t)(2 * jj) * HWn],
                                     xp[(size_t)(2 * jj + 1) * HWn]);
            } else {                     // mixed X / im2col / zero
                float v[8];
                #pragma unroll
                for (int jj = 0; jj < 8; ++jj)
                    v[jj] = fetchU(Xb, plane, mA, c1 + koA * 8 + jj);
                #pragma unroll
                for (int jj = 0; jj < 4; ++jj)
                    pk[jj] = pack2bf(v[2 * jj], v[2 * jj + 1]);
            }
            *(uint4*)&As[(cur ^ 1) * (64 * 40) + mA * 40 + koA * 8] =
                make_uint4(pk[0], pk[1], pk[2], pk[3]);
        }

        // (3) MFMA
        #pragma unroll
        for (int mf = 0; mf < 4; ++mf)
            #pragma unroll
            for (int nf = 0; nf < 4; ++nf)
                acc[mf][nf] = __builtin_amdgcn_mfma_f32_16x16x32_bf16(
                    af[mf], bfr[nf], acc[mf][nf], 0, 0, 0);

        // (4) single barrier: drains DMA/ds_write for next, protects buffers
        __syncthreads();
    }

    // ---- epilogue: e[m] = sum_n Wv[n]*tanh(acc + query[n]); partial over 256 a
    float ep[16];
    #pragma unroll
    for (int i = 0; i < 16; ++i) ep[i] = 0.f;
    #pragma unroll
    for (int nf = 0; nf < 4; ++nf) {
        int nl = w * 64 + nf * 16 + r;
        float qv = qs[nl], wv = wvs[nl];
        #pragma unroll
        for (int mf = 0; mf < 4; ++mf)
            #pragma unroll
            for (int rg = 0; rg < 4; ++rg) {
                float x = acc[mf][nf][rg] + qv;
                float e2 = __expf(2.f * x);
                float th = 1.f - 2.f * __builtin_amdgcn_rcpf(e2 + 1.f);
                ep[mf * 4 + rg] += wv * th;
            }
    }
    float* red = (float*)Bs;   // 64 x 65 floats, Bs free after loop
    #pragma unroll
    for (int mf = 0; mf < 4; ++mf)
        #pragma unroll
        for (int rg = 0; rg < 4; ++rg)
            red[(mf * 16 + q * 4 + rg) * 65 + w * 16 + r] = ep[mf * 4 + rg];
    __syncthreads();
    if (t < 64) {
        float s = 0.f;
        #pragma unroll 16
        for (int i = 0; i < 64; ++i) s += red[t * 65 + i];
        atomicAdd(&energy[b * HWn + hh * Wn + t], s);
    }
}

// ---------------------------------------------------------------------------
// K_ctx: fused softmax + context. Grid (171, 32).
// Each block recomputes the (cheap) per-batch softmax from energy, then
// computes 4 context channels; block x==0 also writes alpha / alpha_sum_new.
__global__ __launch_bounds__(256) void k_ctx(
    const float* __restrict__ X,
    const float* __restrict__ energy,
    const float* __restrict__ mask,
    const float* __restrict__ asum,
    float* __restrict__ out)
{
    __shared__ float al[1024];
    __shared__ float rsm[8];
    const int bx = blockIdx.x, b = blockIdx.y;
    const int t = threadIdx.x, lane = t & 63, wid = t >> 6;

    float e[4], ex[4];
    #pragma unroll
    for (int i = 0; i < 4; ++i) e[i] = energy[b * HWn + i * 256 + t];
    float m = fmaxf(fmaxf(e[0], e[1]), fmaxf(e[2], e[3]));
    for (int off = 32; off >= 1; off >>= 1) m = fmaxf(m, __shfl_down(m, off, 64));
    if (lane == 0) rsm[wid] = m;
    __syncthreads();
    if (t == 0)
        rsm[4] = fmaxf(fmaxf(rsm[0], rsm[1]), fmaxf(rsm[2], rsm[3]));
    __syncthreads();
    const float M = rsm[4];
    float s = 0.f;
    #pragma unroll
    for (int i = 0; i < 4; ++i) {
        ex[i] = expf(e[i] - M) * mask[b * HWn + i * 256 + t];
        s += ex[i];
    }
    for (int off = 32; off >= 1; off >>= 1) s += __shfl_down(s, off, 64);
    __syncthreads();
    if (lane == 0) rsm[wid] = s;
    __syncthreads();
    if (t == 0) rsm[5] = rsm[0] + rsm[1] + rsm[2] + rsm[3] + 1e-10f;
    __syncthreads();
    const float denom = rsm[5];
    #pragma unroll
    for (int i = 0; i < 4; ++i) al[i * 256 + t] = ex[i] / denom;
    __syncthreads();

    // context: wave wid handles channel c
    const int c = bx * 4 + wid;
    const float* xp = X + ((size_t)(b * Cn + c)) * HWn;
    float s2 = 0.f;
    #pragma unroll
    for (int i = 0; i < 4; ++i) {
        int off = i * 256 + lane * 4;
        float4 x = *(const float4*)(xp + off);
        float4 a = *(const float4*)(al + off);
        s2 = fmaf(a.x, x.x, s2);
        s2 = fmaf(a.y, x.y, s2);
        s2 = fmaf(a.z, x.z, s2);
        s2 = fmaf(a.w, x.w, s2);
    }
    for (int off = 32; off >= 1; off >>= 1) s2 += __shfl_down(s2, off, 64);
    if (lane == 0) out[b * Cn + c] = s2;

    if (bx == 0) {
        #pragma unroll
        for (int i = 0; i < 4; ++i) {
            int p = i * 256 + t;
            float a = al[p];
            out[OUT_ALPHA + b * HWn + p] = a;
            out[OUT_ASUM  + b * HWn + p] = a + asum[b * HWn + p];
        }
    }
}

// ---------------------------------------------------------------------------
extern "C" void kernel_launch(void* const* d_in, const int* in_sizes, int n_in,
                              void* d_out, int out_size, void* d_ws, size_t ws_size,
                              hipStream_t stream)
{
    const float* X      = (const float*)d_in[0];
    const float* hidden = (const float*)d_in[1];
    const float* asum   = (const float*)d_in[2];
    const float* mask   = (const float*)d_in[3];
    const float* Wh     = (const float*)d_in[4];
    const float* bh     = (const float*)d_in[5];
    const float* Wec    = (const float*)d_in[6];
    const float* bec    = (const float*)d_in[7];
    const float* Wac    = (const float*)d_in[8];
    const float* Waw    = (const float*)d_in[9];
    const float* Wv     = (const float*)d_in[10];
    (void)in_sizes; (void)n_in; (void)out_size; (void)ws_size;

    float* out = (float*)d_out;
    float* ws = (float*)d_ws;
    float* query  = ws;                                    // 16384 floats
    float* energy = ws + 16384;                            // 32768
    unsigned short* VTbf = (unsigned short*)(ws + 16384 + 32768); // 512*832

    hipMemsetAsync(energy, 0, HWn * Bn * sizeof(float), stream);
    k_prep   <<<dim3(544),      dim3(256), 0, stream>>>(hidden, Wh, bh, bec,
                                                        Wec, Wac, Waw, query, VTbf);
    k_energy <<<dim3(2, 16, 32), dim3(256), 0, stream>>>(X, asum, Wv, query, VTbf, energy);
    k_ctx    <<<dim3(171, 32),  dim3(256), 0, stream>>>(X, energy, mask, asum, out);
}